// Round 1
// baseline (1067.450 us; speedup 1.0000x reference)
//
#include <hip/hip_runtime.h>
#include <cstdint>
#include <cstddef>

#define N_NODES 50000
#define N_EDGES 800000
#define IN_F    128
#define HID     32
#define HEADS   8
#define OUT_F   40
#define D1      256   // HID*HEADS

// ---------------- CSR build (by dst) ----------------
__global__ void k_count(const int* __restrict__ ei, int* __restrict__ deg) {
    int e = blockIdx.x * blockDim.x + threadIdx.x;
    if (e < N_EDGES) atomicAdd(&deg[ei[N_EDGES + e]], 1);
}

__global__ void k_alloc(const int* __restrict__ deg, int* __restrict__ rowstart,
                        int* __restrict__ gcur) {
    int n = blockIdx.x * blockDim.x + threadIdx.x;
    if (n < N_NODES) rowstart[n] = atomicAdd(gcur, deg[n]);
}

__global__ void k_fill(const int* __restrict__ ei, const int* __restrict__ rowstart,
                       int* __restrict__ cursor, int* __restrict__ col) {
    int e = blockIdx.x * blockDim.x + threadIdx.x;
    if (e < N_EDGES) {
        int d = ei[N_EDGES + e];
        int p = atomicAdd(&cursor[d], 1);
        col[rowstart[d] + p] = ei[e];   // store src node id
    }
}

// ---------------- fp32 tiled GEMM: C[M,Nn] = A[M,K] @ B[K,Nn] + bias ----------------
__global__ __launch_bounds__(256) void gemm_bias(
        const float* __restrict__ A, const float* __restrict__ B,
        const float* __restrict__ bias, float* __restrict__ C,
        int M, int K, int Nn) {
    constexpr int TM = 64, TN = 64, TK = 16;
    __shared__ float As[TK][TM];
    __shared__ float Bs[TK][TN];
    int tid = threadIdx.x;
    int bm = blockIdx.x * TM;
    int bn = blockIdx.y * TN;
    int tx = tid & 15, ty = tid >> 4;
    float acc[4][4] = {};
    for (int k0 = 0; k0 < K; k0 += TK) {
#pragma unroll
        for (int i = 0; i < 4; ++i) {          // A tile: 64x16
            int idx = tid + i * 256;
            int am = idx >> 4, ak = idx & 15;
            int gm = bm + am;
            As[ak][am] = (gm < M) ? A[(size_t)gm * K + k0 + ak] : 0.f;
        }
#pragma unroll
        for (int i = 0; i < 4; ++i) {          // B tile: 16x64
            int idx = tid + i * 256;
            int bk = idx >> 6, bnn = idx & 63;
            int gn = bn + bnn;
            Bs[bk][bnn] = (gn < Nn) ? B[(size_t)(k0 + bk) * Nn + gn] : 0.f;
        }
        __syncthreads();
#pragma unroll
        for (int kk = 0; kk < TK; ++kk) {
            float a[4], b[4];
#pragma unroll
            for (int i = 0; i < 4; ++i) a[i] = As[kk][ty * 4 + i];
#pragma unroll
            for (int i = 0; i < 4; ++i) b[i] = Bs[kk][tx * 4 + i];
#pragma unroll
            for (int i = 0; i < 4; ++i)
#pragma unroll
                for (int j = 0; j < 4; ++j)
                    acc[i][j] += a[i] * b[j];
        }
        __syncthreads();
    }
#pragma unroll
    for (int i = 0; i < 4; ++i) {
        int gm = bm + ty * 4 + i;
        if (gm >= M) continue;
#pragma unroll
        for (int j = 0; j < 4; ++j) {
            int gn = bn + tx * 4 + j;
            if (gn < Nn) C[(size_t)gm * Nn + gn] = acc[i][j] + bias[gn];
        }
    }
}

// ---------------- layer-1 edge kernel: one wave per dst node ----------------
// lane owns channels [4*lane, 4*lane+3]; head = lane>>3 (8 lanes/head, 32 ch/head)
__global__ __launch_bounds__(256) void k_edge1(
        const float* __restrict__ Q, const float* __restrict__ K,
        const float* __restrict__ V, const float* __restrict__ S,
        const float* __restrict__ bw,
        const int* __restrict__ rowstart, const int* __restrict__ deg,
        const int* __restrict__ col, float* __restrict__ H1) {
    int gid  = blockIdx.x * blockDim.x + threadIdx.x;
    int node = gid >> 6;
    int lane = threadIdx.x & 63;
    if (node >= N_NODES) return;
    const int c4 = lane * 4;
    const float scale = 0.17677669529663687f;  // 1/sqrt(32)
    float4 q = *reinterpret_cast<const float4*>(Q + (size_t)node * D1 + c4);
    q.x *= scale; q.y *= scale; q.z *= scale; q.w *= scale;

    float m = -INFINITY, l = 0.f;
    float4 acc = make_float4(0.f, 0.f, 0.f, 0.f);
    int start = rowstart[node];
    int d = deg[node];
    for (int t = 0; t < d; ++t) {
        int j = col[start + t];
        float4 kk = *reinterpret_cast<const float4*>(K + (size_t)j * D1 + c4);
        float part = q.x * kk.x + q.y * kk.y + q.z * kk.z + q.w * kk.w;
        part += __shfl_xor(part, 1);
        part += __shfl_xor(part, 2);
        part += __shfl_xor(part, 4);   // alpha for this lane's head
        float nm = fmaxf(m, part);
        float f  = __expf(m - nm);     // exp(-inf)=0 on first edge
        float p  = __expf(part - nm);
        l = l * f + p;
        float4 vv = *reinterpret_cast<const float4*>(V + (size_t)j * D1 + c4);
        acc.x = acc.x * f + p * vv.x;
        acc.y = acc.y * f + p * vv.y;
        acc.z = acc.z * f + p * vv.z;
        acc.w = acc.w * f + p * vv.w;
        m = nm;
    }
    float inv = (l > 0.f) ? 1.f / l : 0.f;
    float4 o = make_float4(acc.x * inv, acc.y * inv, acc.z * inv, acc.w * inv);
    float4 sk = *reinterpret_cast<const float4*>(S + (size_t)node * D1 + c4);
    float4 w0 = *reinterpret_cast<const float4*>(bw + c4);
    float4 w1 = *reinterpret_cast<const float4*>(bw + D1 + c4);
    float4 w2 = *reinterpret_cast<const float4*>(bw + 2 * D1 + c4);
    float part = o.x * w0.x + o.y * w0.y + o.z * w0.z + o.w * w0.w
               + sk.x * w1.x + sk.y * w1.y + sk.z * w1.z + sk.w * w1.w
               + (o.x - sk.x) * w2.x + (o.y - sk.y) * w2.y
               + (o.z - sk.z) * w2.z + (o.w - sk.w) * w2.w;
#pragma unroll
    for (int s = 1; s < 64; s <<= 1) part += __shfl_xor(part, s);
    float beta = 1.f / (1.f + __expf(-part));
    float4 h;
    h.x = beta * sk.x + (1.f - beta) * o.x;
    h.y = beta * sk.y + (1.f - beta) * o.y;
    h.z = beta * sk.z + (1.f - beta) * o.z;
    h.w = beta * sk.w + (1.f - beta) * o.w;
    // ELU (alpha=1)
    h.x = h.x > 0.f ? h.x : __expf(h.x) - 1.f;
    h.y = h.y > 0.f ? h.y : __expf(h.y) - 1.f;
    h.z = h.z > 0.f ? h.z : __expf(h.z) - 1.f;
    h.w = h.w > 0.f ? h.w : __expf(h.w) - 1.f;
    *reinterpret_cast<float4*>(H1 + (size_t)node * D1 + c4) = h;
}

// ---------------- layer-2 edge kernel: one wave per dst node, 40 channels ----------------
__global__ __launch_bounds__(256) void k_edge2(
        const float* __restrict__ Q, const float* __restrict__ K,
        const float* __restrict__ V, const float* __restrict__ S,
        const float* __restrict__ bw,
        const int* __restrict__ rowstart, const int* __restrict__ deg,
        const int* __restrict__ col, float* __restrict__ out) {
    int gid  = blockIdx.x * blockDim.x + threadIdx.x;
    int node = gid >> 6;
    int lane = threadIdx.x & 63;
    if (node >= N_NODES) return;
    bool act = lane < OUT_F;
    const float scale = 0.15811388300841897f;  // 1/sqrt(40)
    float q = act ? Q[(size_t)node * OUT_F + lane] * scale : 0.f;

    float m = -INFINITY, l = 0.f, acc = 0.f;
    int start = rowstart[node];
    int d = deg[node];
    for (int t = 0; t < d; ++t) {
        int j = col[start + t];
        float kk = act ? K[(size_t)j * OUT_F + lane] : 0.f;
        float part = q * kk;
#pragma unroll
        for (int s = 1; s < 64; s <<= 1) part += __shfl_xor(part, s);
        float nm = fmaxf(m, part);
        float f  = __expf(m - nm);
        float p  = __expf(part - nm);
        l = l * f + p;
        float vv = act ? V[(size_t)j * OUT_F + lane] : 0.f;
        acc = acc * f + p * vv;
        m = nm;
    }
    float inv = (l > 0.f) ? 1.f / l : 0.f;
    float o  = acc * inv;
    float sk = act ? S[(size_t)node * OUT_F + lane] : 0.f;
    float part = act ? (o * bw[lane] + sk * bw[OUT_F + lane] + (o - sk) * bw[2 * OUT_F + lane]) : 0.f;
#pragma unroll
    for (int s = 1; s < 64; s <<= 1) part += __shfl_xor(part, s);
    float beta = 1.f / (1.f + __expf(-part));
    if (act) out[(size_t)node * OUT_F + lane] = beta * sk + (1.f - beta) * o;
}

// ---------------- launch ----------------
extern "C" void kernel_launch(void* const* d_in, const int* in_sizes, int n_in,
                              void* d_out, int out_size, void* d_ws, size_t ws_size,
                              hipStream_t stream) {
    const float* x   = (const float*)d_in[0];
    const int*   ei  = (const int*)d_in[1];
    const float* q1w = (const float*)d_in[2];
    const float* q1b = (const float*)d_in[3];
    const float* k1w = (const float*)d_in[4];
    const float* k1b = (const float*)d_in[5];
    const float* v1w = (const float*)d_in[6];
    const float* v1b = (const float*)d_in[7];
    const float* s1w = (const float*)d_in[8];
    const float* s1b = (const float*)d_in[9];
    const float* b1w = (const float*)d_in[10];
    const float* q2w = (const float*)d_in[11];
    const float* q2b = (const float*)d_in[12];
    const float* k2w = (const float*)d_in[13];
    const float* k2b = (const float*)d_in[14];
    const float* v2w = (const float*)d_in[15];
    const float* v2b = (const float*)d_in[16];
    const float* s2w = (const float*)d_in[17];
    const float* s2b = (const float*)d_in[18];
    const float* b2w = (const float*)d_in[19];
    float* out = (float*)d_out;

    // workspace layout (floats), layer-2 buffers alias layer-1 (dead by then)
    size_t fN1 = (size_t)N_NODES * D1;          // 12.8M floats each
    float* Q1 = (float*)d_ws;
    float* K1 = Q1 + fN1;
    float* V1 = K1 + fN1;
    float* S1 = V1 + fN1;
    float* H1 = S1 + fN1;
    float* Q2 = Q1;  float* K2 = K1;  float* V2 = V1;  float* S2 = S1;
    int* ibase    = (int*)(H1 + fN1);
    int* deg      = ibase;
    int* cursor   = deg + N_NODES;
    int* gcur     = cursor + N_NODES;
    int* rowstart = gcur + 1;
    int* col      = rowstart + N_NODES;

    // zero deg, cursor, gcur
    hipMemsetAsync(deg, 0, (2 * (size_t)N_NODES + 1) * sizeof(int), stream);

    k_count<<<(N_EDGES + 255) / 256, 256, 0, stream>>>(ei, deg);
    k_alloc<<<(N_NODES + 255) / 256, 256, 0, stream>>>(deg, rowstart, gcur);
    k_fill <<<(N_EDGES + 255) / 256, 256, 0, stream>>>(ei, rowstart, cursor, col);

    dim3 g1((N_NODES + 63) / 64, (D1 + 63) / 64);
    gemm_bias<<<g1, 256, 0, stream>>>(x, q1w, q1b, Q1, N_NODES, IN_F, D1);
    gemm_bias<<<g1, 256, 0, stream>>>(x, k1w, k1b, K1, N_NODES, IN_F, D1);
    gemm_bias<<<g1, 256, 0, stream>>>(x, v1w, v1b, V1, N_NODES, IN_F, D1);
    gemm_bias<<<g1, 256, 0, stream>>>(x, s1w, s1b, S1, N_NODES, IN_F, D1);

    k_edge1<<<(N_NODES * 64) / 256, 256, 0, stream>>>(Q1, K1, V1, S1, b1w,
                                                      rowstart, deg, col, H1);

    dim3 g2((N_NODES + 63) / 64, (OUT_F + 63) / 64);
    gemm_bias<<<g2, 256, 0, stream>>>(H1, q2w, q2b, Q2, N_NODES, D1, OUT_F);
    gemm_bias<<<g2, 256, 0, stream>>>(H1, k2w, k2b, K2, N_NODES, D1, OUT_F);
    gemm_bias<<<g2, 256, 0, stream>>>(H1, v2w, v2b, V2, N_NODES, D1, OUT_F);
    gemm_bias<<<g2, 256, 0, stream>>>(H1, s2w, s2b, S2, N_NODES, D1, OUT_F);

    k_edge2<<<(N_NODES * 64) / 256, 256, 0, stream>>>(Q2, K2, V2, S2, b2w,
                                                      rowstart, deg, col, out);
}

// Round 2
// 702.557 us; speedup vs baseline: 1.5194x; 1.5194x over previous
//
#include <hip/hip_runtime.h>
#include <cstdint>
#include <cstddef>

#define N_NODES 50000
#define N_EDGES 800000
#define IN_F    128
#define HID     32
#define HEADS   8
#define OUT_F   40
#define D1      256   // HID*HEADS
#define W1COLS  1024  // 4*D1
#define W2COLS  160   // 4*OUT_F

typedef unsigned short ushortT;
typedef unsigned short ushortx8 __attribute__((ext_vector_type(8)));
typedef __bf16 bf16x8 __attribute__((ext_vector_type(8)));
typedef float floatx4 __attribute__((ext_vector_type(4)));

__device__ inline ushortT f2bf(float f) {
    union { float f; unsigned int u; } c; c.f = f;
    unsigned int r = c.u + 0x7FFFu + ((c.u >> 16) & 1u);
    return (ushortT)(r >> 16);
}

// ---------------- CSR build (by dst) ----------------
__global__ void k_count(const int* __restrict__ ei, int* __restrict__ deg) {
    int e = blockIdx.x * blockDim.x + threadIdx.x;
    if (e < N_EDGES) atomicAdd(&deg[ei[N_EDGES + e]], 1);
}

__global__ void k_alloc(const int* __restrict__ deg, int* __restrict__ rowstart,
                        int* __restrict__ gcur) {
    int n = blockIdx.x * blockDim.x + threadIdx.x;
    if (n < N_NODES) rowstart[n] = atomicAdd(gcur, deg[n]);
}

__global__ void k_fill(const int* __restrict__ ei, const int* __restrict__ rowstart,
                       int* __restrict__ cursor, int* __restrict__ col) {
    int e = blockIdx.x * blockDim.x + threadIdx.x;
    if (e < N_EDGES) {
        int d = ei[N_EDGES + e];
        int p = atomicAdd(&cursor[d], 1);
        col[rowstart[d] + p] = ei[e];   // store src node id
    }
}

// ---------------- conversions ----------------
__global__ void conv_x_bf16(const float* __restrict__ x, ushortT* __restrict__ xb) {
    int i = blockIdx.x * blockDim.x + threadIdx.x;   // over N*IN/4 float4s
    if (i >= N_NODES * IN_F / 4) return;
    float4 v = reinterpret_cast<const float4*>(x)[i];
    ushort4 o;
    o.x = f2bf(v.x); o.y = f2bf(v.y); o.z = f2bf(v.z); o.w = f2bf(v.w);
    reinterpret_cast<ushort4*>(xb)[i] = o;
}

// W1T[c][k] = w_sel[k][c%256], c in [0,1024), k in [0,128)
__global__ void build_w1(const float* __restrict__ qw, const float* __restrict__ kw,
                         const float* __restrict__ vw, const float* __restrict__ sw,
                         const float* __restrict__ qb, const float* __restrict__ kb,
                         const float* __restrict__ vb, const float* __restrict__ sb,
                         ushortT* __restrict__ WT, float* __restrict__ bcat) {
    int t = blockIdx.x * blockDim.x + threadIdx.x;
    if (t >= W1COLS * IN_F) return;
    int c = t / IN_F, k = t % IN_F;
    int sel = c >> 8, cc = c & 255;
    const float* w = sel == 0 ? qw : sel == 1 ? kw : sel == 2 ? vw : sw;
    WT[(size_t)c * IN_F + k] = f2bf(w[(size_t)k * D1 + cc]);
    if (k == 0) {
        const float* b = sel == 0 ? qb : sel == 1 ? kb : sel == 2 ? vb : sb;
        bcat[c] = b[cc];
    }
}

// W2T[c][k] = w_sel[k][c%40], c in [0,160), k in [0,256)
__global__ void build_w2(const float* __restrict__ qw, const float* __restrict__ kw,
                         const float* __restrict__ vw, const float* __restrict__ sw,
                         const float* __restrict__ qb, const float* __restrict__ kb,
                         const float* __restrict__ vb, const float* __restrict__ sb,
                         ushortT* __restrict__ WT, float* __restrict__ bcat) {
    int t = blockIdx.x * blockDim.x + threadIdx.x;
    if (t >= W2COLS * D1) return;
    int c = t / D1, k = t % D1;
    int sel = c / OUT_F, cc = c % OUT_F;
    const float* w = sel == 0 ? qw : sel == 1 ? kw : sel == 2 ? vw : sw;
    WT[(size_t)c * D1 + k] = f2bf(w[(size_t)k * OUT_F + cc]);
    if (k == 0) {
        const float* b = sel == 0 ? qb : sel == 1 ? kb : sel == 2 ? vb : sb;
        bcat[c] = b[cc];
    }
}

// ---------------- bf16 MFMA GEMM: C[M][Nn] = A[M][K] @ BT[Nn][K]^T + bias ----------------
// 128x128 tile, TK=64, 4 waves (2x2), each wave 64x64 via 4x4 mfma_f32_16x16x32_bf16
__global__ __launch_bounds__(256) void gemm_mfma_bt(
        const ushortT* __restrict__ A, const ushortT* __restrict__ BT,
        const float* __restrict__ bias, float* __restrict__ C,
        int M, int K, int Nn) {
    constexpr int TM = 128, TN = 128, TK = 64, LDP = 72;  // LDS row stride (pad 8)
    __shared__ ushortT As[TM * LDP];
    __shared__ ushortT Bs[TN * LDP];
    int tid = threadIdx.x;
    int lane = tid & 63, wave = tid >> 6;
    int bm = blockIdx.x * TM, bn = blockIdx.y * TN;
    int wm = (wave & 1) * 64, wn = (wave >> 1) * 64;
    int mrow = lane & 15, g = lane >> 4;
    floatx4 acc[4][4] = {};

    for (int k0 = 0; k0 < K; k0 += TK) {
        // stage A tile 128x64 (each thread: 4x 16B loads)
#pragma unroll
        for (int it = 0; it < 4; ++it) {
            int idx = tid + it * 256;
            int r = idx >> 3, c = (idx & 7) * 8;
            int gm = bm + r;
            ushortx8 val;
            if (gm < M) val = *reinterpret_cast<const ushortx8*>(A + (size_t)gm * K + k0 + c);
            else        val = (ushortx8)0;
            *reinterpret_cast<ushortx8*>(As + r * LDP + c) = val;
        }
        // stage B tile 128x64 from BT (row-major in K)
#pragma unroll
        for (int it = 0; it < 4; ++it) {
            int idx = tid + it * 256;
            int r = idx >> 3, c = (idx & 7) * 8;
            int gn = bn + r;
            ushortx8 val;
            if (gn < Nn) val = *reinterpret_cast<const ushortx8*>(BT + (size_t)gn * K + k0 + c);
            else         val = (ushortx8)0;
            *reinterpret_cast<ushortx8*>(Bs + r * LDP + c) = val;
        }
        __syncthreads();
#pragma unroll
        for (int kc = 0; kc < TK / 32; ++kc) {
            bf16x8 a[4], b[4];
#pragma unroll
            for (int i = 0; i < 4; ++i)
                a[i] = *reinterpret_cast<const bf16x8*>(As + (wm + i * 16 + mrow) * LDP + kc * 32 + g * 8);
#pragma unroll
            for (int j = 0; j < 4; ++j)
                b[j] = *reinterpret_cast<const bf16x8*>(Bs + (wn + j * 16 + mrow) * LDP + kc * 32 + g * 8);
#pragma unroll
            for (int i = 0; i < 4; ++i)
#pragma unroll
                for (int j = 0; j < 4; ++j)
                    acc[i][j] = __builtin_amdgcn_mfma_f32_16x16x32_bf16(a[i], b[j], acc[i][j], 0, 0, 0);
        }
        __syncthreads();
    }
    // epilogue: C/D layout col=lane&15, row=g*4+reg
#pragma unroll
    for (int i = 0; i < 4; ++i) {
#pragma unroll
        for (int j = 0; j < 4; ++j) {
            int gn = bn + wn + j * 16 + mrow;
            if (gn >= Nn) continue;
            float bv = bias[gn];
#pragma unroll
            for (int r = 0; r < 4; ++r) {
                int gm = bm + wm + i * 16 + g * 4 + r;
                if (gm < M) C[(size_t)gm * Nn + gn] = acc[i][j][r] + bv;
            }
        }
    }
}

// ---------------- layer-1 edge kernel: one wave per dst node ----------------
// QKVS row = [Q(256) | K(256) | V(256) | S(256)], stride 1024
__global__ __launch_bounds__(256) void k_edge1(
        const float* __restrict__ QKVS, const float* __restrict__ bw,
        const int* __restrict__ rowstart, const int* __restrict__ deg,
        const int* __restrict__ col, ushortT* __restrict__ H1b) {
    int gid  = blockIdx.x * blockDim.x + threadIdx.x;
    int node = gid >> 6;
    int lane = threadIdx.x & 63;
    if (node >= N_NODES) return;
    const int c4 = lane * 4;
    const float scale = 0.17677669529663687f;  // 1/sqrt(32)
    float4 q = *reinterpret_cast<const float4*>(QKVS + (size_t)node * W1COLS + c4);
    q.x *= scale; q.y *= scale; q.z *= scale; q.w *= scale;

    float m = -INFINITY, l = 0.f;
    float4 acc = make_float4(0.f, 0.f, 0.f, 0.f);
    int start = rowstart[node];
    int d = deg[node];
    for (int t = 0; t < d; ++t) {
        int j = col[start + t];
        const float* rowj = QKVS + (size_t)j * W1COLS;
        float4 kk = *reinterpret_cast<const float4*>(rowj + D1 + c4);
        float part = q.x * kk.x + q.y * kk.y + q.z * kk.z + q.w * kk.w;
        part += __shfl_xor(part, 1);
        part += __shfl_xor(part, 2);
        part += __shfl_xor(part, 4);   // alpha for this lane's head
        float nm = fmaxf(m, part);
        float f  = __expf(m - nm);
        float p  = __expf(part - nm);
        l = l * f + p;
        float4 vv = *reinterpret_cast<const float4*>(rowj + 2 * D1 + c4);
        acc.x = acc.x * f + p * vv.x;
        acc.y = acc.y * f + p * vv.y;
        acc.z = acc.z * f + p * vv.z;
        acc.w = acc.w * f + p * vv.w;
        m = nm;
    }
    float inv = (l > 0.f) ? 1.f / l : 0.f;
    float4 o = make_float4(acc.x * inv, acc.y * inv, acc.z * inv, acc.w * inv);
    float4 sk = *reinterpret_cast<const float4*>(QKVS + (size_t)node * W1COLS + 3 * D1 + c4);
    float4 w0 = *reinterpret_cast<const float4*>(bw + c4);
    float4 w1 = *reinterpret_cast<const float4*>(bw + D1 + c4);
    float4 w2 = *reinterpret_cast<const float4*>(bw + 2 * D1 + c4);
    float part = o.x * w0.x + o.y * w0.y + o.z * w0.z + o.w * w0.w
               + sk.x * w1.x + sk.y * w1.y + sk.z * w1.z + sk.w * w1.w
               + (o.x - sk.x) * w2.x + (o.y - sk.y) * w2.y
               + (o.z - sk.z) * w2.z + (o.w - sk.w) * w2.w;
#pragma unroll
    for (int s = 1; s < 64; s <<= 1) part += __shfl_xor(part, s);
    float beta = 1.f / (1.f + __expf(-part));
    float4 h;
    h.x = beta * sk.x + (1.f - beta) * o.x;
    h.y = beta * sk.y + (1.f - beta) * o.y;
    h.z = beta * sk.z + (1.f - beta) * o.z;
    h.w = beta * sk.w + (1.f - beta) * o.w;
    // ELU (alpha=1)
    h.x = h.x > 0.f ? h.x : __expf(h.x) - 1.f;
    h.y = h.y > 0.f ? h.y : __expf(h.y) - 1.f;
    h.z = h.z > 0.f ? h.z : __expf(h.z) - 1.f;
    h.w = h.w > 0.f ? h.w : __expf(h.w) - 1.f;
    ushort4 hb;
    hb.x = f2bf(h.x); hb.y = f2bf(h.y); hb.z = f2bf(h.z); hb.w = f2bf(h.w);
    *reinterpret_cast<ushort4*>(H1b + (size_t)node * D1 + c4) = hb;
}

// ---------------- layer-2 edge kernel: one wave per dst node, 40 channels ----------------
// C2 row = [Q(40) | K(40) | V(40) | S(40)], stride 160
__global__ __launch_bounds__(256) void k_edge2(
        const float* __restrict__ C2, const float* __restrict__ bw,
        const int* __restrict__ rowstart, const int* __restrict__ deg,
        const int* __restrict__ col, float* __restrict__ out) {
    int gid  = blockIdx.x * blockDim.x + threadIdx.x;
    int node = gid >> 6;
    int lane = threadIdx.x & 63;
    if (node >= N_NODES) return;
    bool act = lane < OUT_F;
    int ln = act ? lane : 0;
    const float scale = 0.15811388300841897f;  // 1/sqrt(40)
    float q = act ? C2[(size_t)node * W2COLS + ln] * scale : 0.f;

    float m = -INFINITY, l = 0.f, acc = 0.f;
    int start = rowstart[node];
    int d = deg[node];
    for (int t = 0; t < d; ++t) {
        int j = col[start + t];
        const float* rowj = C2 + (size_t)j * W2COLS;
        float kk = act ? rowj[OUT_F + ln] : 0.f;
        float part = q * kk;
#pragma unroll
        for (int s = 1; s < 64; s <<= 1) part += __shfl_xor(part, s);
        float nm = fmaxf(m, part);
        float f  = __expf(m - nm);
        float p  = __expf(part - nm);
        l = l * f + p;
        float vv = act ? rowj[2 * OUT_F + ln] : 0.f;
        acc = acc * f + p * vv;
        m = nm;
    }
    float inv = (l > 0.f) ? 1.f / l : 0.f;
    float o  = acc * inv;
    float sk = act ? C2[(size_t)node * W2COLS + 3 * OUT_F + ln] : 0.f;
    float part = act ? (o * bw[ln] + sk * bw[OUT_F + ln] + (o - sk) * bw[2 * OUT_F + ln]) : 0.f;
#pragma unroll
    for (int s = 1; s < 64; s <<= 1) part += __shfl_xor(part, s);
    float beta = 1.f / (1.f + __expf(-part));
    if (act) out[(size_t)node * OUT_F + lane] = beta * sk + (1.f - beta) * o;
}

// ---------------- launch ----------------
extern "C" void kernel_launch(void* const* d_in, const int* in_sizes, int n_in,
                              void* d_out, int out_size, void* d_ws, size_t ws_size,
                              hipStream_t stream) {
    const float* x   = (const float*)d_in[0];
    const int*   ei  = (const int*)d_in[1];
    const float* q1w = (const float*)d_in[2];
    const float* q1b = (const float*)d_in[3];
    const float* k1w = (const float*)d_in[4];
    const float* k1b = (const float*)d_in[5];
    const float* v1w = (const float*)d_in[6];
    const float* v1b = (const float*)d_in[7];
    const float* s1w = (const float*)d_in[8];
    const float* s1b = (const float*)d_in[9];
    const float* b1w = (const float*)d_in[10];
    const float* q2w = (const float*)d_in[11];
    const float* q2b = (const float*)d_in[12];
    const float* k2w = (const float*)d_in[13];
    const float* k2b = (const float*)d_in[14];
    const float* v2w = (const float*)d_in[15];
    const float* v2b = (const float*)d_in[16];
    const float* s2w = (const float*)d_in[17];
    const float* s2b = (const float*)d_in[18];
    const float* b2w = (const float*)d_in[19];
    float* out = (float*)d_out;

    // ---- workspace layout (byte offsets, all 16B aligned) ----
    char* w = (char*)d_ws;
    float*   QKVS1 = (float*)w;                          // 50000*1024*4 = 204,800,000
    float*   C2    = QKVS1;                              // alias (QKVS1 dead after edge1)
    ushortT* H1b   = (ushortT*)(w + 204800000);          // 50000*256*2  =  25,600,000
    ushortT* xb    = (ushortT*)(w + 230400000);          // 50000*128*2  =  12,800,000
    ushortT* W1T   = (ushortT*)(w + 243200000);          // 1024*128*2   =     262,144
    ushortT* W2T   = (ushortT*)(w + 243462144);          // 160*256*2    =      81,920
    float*   b1c   = (float*)(w + 243544064);            // 1024*4       =       4,096
    float*   b2c   = (float*)(w + 243548160);            // 160*4 (pad to 1024)
    int* deg      = (int*)(w + 243549184);
    int* cursor   = deg + N_NODES;
    int* gcur     = cursor + N_NODES;
    int* rowstart = gcur + 1;
    int* col      = rowstart + N_NODES;

    hipMemsetAsync(deg, 0, (2 * (size_t)N_NODES + 1) * sizeof(int), stream);

    k_count<<<(N_EDGES + 255) / 256, 256, 0, stream>>>(ei, deg);
    k_alloc<<<(N_NODES + 255) / 256, 256, 0, stream>>>(deg, rowstart, gcur);
    k_fill <<<(N_EDGES + 255) / 256, 256, 0, stream>>>(ei, rowstart, cursor, col);

    conv_x_bf16<<<(N_NODES * IN_F / 4 + 255) / 256, 256, 0, stream>>>(x, xb);
    build_w1<<<(W1COLS * IN_F + 255) / 256, 256, 0, stream>>>(
        q1w, k1w, v1w, s1w, q1b, k1b, v1b, s1b, W1T, b1c);
    build_w2<<<(W2COLS * D1 + 255) / 256, 256, 0, stream>>>(
        q2w, k2w, v2w, s2w, q2b, k2b, v2b, s2b, W2T, b2c);

    dim3 g1((N_NODES + 127) / 128, W1COLS / 128);
    gemm_mfma_bt<<<g1, 256, 0, stream>>>(xb, W1T, b1c, QKVS1, N_NODES, IN_F, W1COLS);

    k_edge1<<<(N_NODES * 64) / 256, 256, 0, stream>>>(QKVS1, b1w, rowstart, deg, col, H1b);

    dim3 g2((N_NODES + 127) / 128, (W2COLS + 127) / 128);
    gemm_mfma_bt<<<g2, 256, 0, stream>>>(H1b, W2T, b2c, C2, N_NODES, D1, W2COLS);

    k_edge2<<<(N_NODES * 64) / 256, 256, 0, stream>>>(C2, b2w, rowstart, deg, col, out);
}

// Round 3
// 587.440 us; speedup vs baseline: 1.8171x; 1.1960x over previous
//
#include <hip/hip_runtime.h>
#include <cstdint>
#include <cstddef>

#define N_NODES 50000
#define N_EDGES 800000
#define IN_F    128
#define HID     32
#define HEADS   8
#define OUT_F   40
#define D1      256   // HID*HEADS
#define W1COLS  1024  // 4*D1
#define W2COLS  160   // 4*OUT_F

typedef unsigned short ushortT;
typedef unsigned short ushortx8 __attribute__((ext_vector_type(8)));
typedef __bf16 bf16x8 __attribute__((ext_vector_type(8)));
typedef float floatx4 __attribute__((ext_vector_type(4)));

__device__ inline ushortT f2bf(float f) {
    union { float f; unsigned int u; } c; c.f = f;
    unsigned int r = c.u + 0x7FFFu + ((c.u >> 16) & 1u);
    return (ushortT)(r >> 16);
}
__device__ inline float bf2f(ushortT h) {
    union { unsigned int u; float f; } c; c.u = ((unsigned int)h) << 16; return c.f;
}

// ---------------- CSR build (by dst) ----------------
__global__ void k_count(const int* __restrict__ ei, int* __restrict__ deg) {
    int e = blockIdx.x * blockDim.x + threadIdx.x;
    if (e < N_EDGES) atomicAdd(&deg[ei[N_EDGES + e]], 1);
}

__global__ void k_alloc(const int* __restrict__ deg, int* __restrict__ rowstart,
                        int* __restrict__ gcur) {
    int n = blockIdx.x * blockDim.x + threadIdx.x;
    if (n < N_NODES) rowstart[n] = atomicAdd(gcur, deg[n]);
}

__global__ void k_fill(const int* __restrict__ ei, const int* __restrict__ rowstart,
                       int* __restrict__ cursor, int* __restrict__ col) {
    int e = blockIdx.x * blockDim.x + threadIdx.x;
    if (e < N_EDGES) {
        int d = ei[N_EDGES + e];
        int p = atomicAdd(&cursor[d], 1);
        col[rowstart[d] + p] = ei[e];   // store src node id
    }
}

// ---------------- conversions ----------------
__global__ void conv_x_bf16(const float* __restrict__ x, ushortT* __restrict__ xb) {
    int i = blockIdx.x * blockDim.x + threadIdx.x;   // over N*IN/4 float4s
    if (i >= N_NODES * IN_F / 4) return;
    float4 v = reinterpret_cast<const float4*>(x)[i];
    ushort4 o;
    o.x = f2bf(v.x); o.y = f2bf(v.y); o.z = f2bf(v.z); o.w = f2bf(v.w);
    reinterpret_cast<ushort4*>(xb)[i] = o;
}

// W1T[c][k] = w_sel[k][c%256], c in [0,1024), k in [0,128)
__global__ void build_w1(const float* __restrict__ qw, const float* __restrict__ kw,
                         const float* __restrict__ vw, const float* __restrict__ sw,
                         const float* __restrict__ qb, const float* __restrict__ kb,
                         const float* __restrict__ vb, const float* __restrict__ sb,
                         ushortT* __restrict__ WT, float* __restrict__ bcat) {
    int t = blockIdx.x * blockDim.x + threadIdx.x;
    if (t >= W1COLS * IN_F) return;
    int c = t / IN_F, k = t % IN_F;
    int sel = c >> 8, cc = c & 255;
    const float* w = sel == 0 ? qw : sel == 1 ? kw : sel == 2 ? vw : sw;
    WT[(size_t)c * IN_F + k] = f2bf(w[(size_t)k * D1 + cc]);
    if (k == 0) {
        const float* b = sel == 0 ? qb : sel == 1 ? kb : sel == 2 ? vb : sb;
        bcat[c] = b[cc];
    }
}

// W2T[c][k] = w_sel[k][c%40], c in [0,160), k in [0,256)
__global__ void build_w2(const float* __restrict__ qw, const float* __restrict__ kw,
                         const float* __restrict__ vw, const float* __restrict__ sw,
                         const float* __restrict__ qb, const float* __restrict__ kb,
                         const float* __restrict__ vb, const float* __restrict__ sb,
                         ushortT* __restrict__ WT, float* __restrict__ bcat) {
    int t = blockIdx.x * blockDim.x + threadIdx.x;
    if (t >= W2COLS * D1) return;
    int c = t / D1, k = t % D1;
    int sel = c / OUT_F, cc = c % OUT_F;
    const float* w = sel == 0 ? qw : sel == 1 ? kw : sel == 2 ? vw : sw;
    WT[(size_t)c * D1 + k] = f2bf(w[(size_t)k * OUT_F + cc]);
    if (k == 0) {
        const float* b = sel == 0 ? qb : sel == 1 ? kb : sel == 2 ? vb : sb;
        bcat[c] = b[cc];
    }
}

// ---------------- bf16 MFMA GEMM with packed epilogue ----------------
// C = A[M][K] @ BT[Nn][K]^T + bias, result split into QS (fp32) and KV (bf16 interleaved).
// MODE 1 (layer1, Nn=1024, sections of 256):
//   Q  -> QS[n*512 + c]              (fp32)
//   K  -> KV[n*512 + (c>>2)*8 + (c&3)]     (bf16)
//   V  -> KV[n*512 + (c>>2)*8 + 4 + (c&3)] (bf16)
//   S  -> QS[n*512 + 256 + c]        (fp32)
// MODE 2 (layer2, Nn=160, sections of 40):
//   Q  -> QS[n*80 + c]    K -> KV[n*80 + 2c]    V -> KV[n*80 + 2c+1]    S -> QS[n*80 + 40 + c]
template<int MODE>
__global__ __launch_bounds__(256) void gemm_mfma_pack(
        const ushortT* __restrict__ A, const ushortT* __restrict__ BT,
        const float* __restrict__ bias, float* __restrict__ QS,
        ushortT* __restrict__ KV, int M, int K, int Nn) {
    constexpr int TM = 128, TN = 128, TK = 64, LDP = 72;  // LDS row stride (pad 8)
    __shared__ ushortT As[TM * LDP];
    __shared__ ushortT Bs[TN * LDP];
    int tid = threadIdx.x;
    int lane = tid & 63, wave = tid >> 6;
    int bm = blockIdx.x * TM, bn = blockIdx.y * TN;
    int wm = (wave & 1) * 64, wn = (wave >> 1) * 64;
    int mrow = lane & 15, g = lane >> 4;
    floatx4 acc[4][4] = {};

    for (int k0 = 0; k0 < K; k0 += TK) {
#pragma unroll
        for (int it = 0; it < 4; ++it) {          // A tile: 128x64
            int idx = tid + it * 256;
            int r = idx >> 3, c = (idx & 7) * 8;
            int gm = bm + r;
            ushortx8 val;
            if (gm < M) val = *reinterpret_cast<const ushortx8*>(A + (size_t)gm * K + k0 + c);
            else        val = (ushortx8)0;
            *reinterpret_cast<ushortx8*>(As + r * LDP + c) = val;
        }
#pragma unroll
        for (int it = 0; it < 4; ++it) {          // B tile: 128x64
            int idx = tid + it * 256;
            int r = idx >> 3, c = (idx & 7) * 8;
            int gn = bn + r;
            ushortx8 val;
            if (gn < Nn) val = *reinterpret_cast<const ushortx8*>(BT + (size_t)gn * K + k0 + c);
            else         val = (ushortx8)0;
            *reinterpret_cast<ushortx8*>(Bs + r * LDP + c) = val;
        }
        __syncthreads();
#pragma unroll
        for (int kc = 0; kc < TK / 32; ++kc) {
            bf16x8 a[4], b[4];
#pragma unroll
            for (int i = 0; i < 4; ++i)
                a[i] = *reinterpret_cast<const bf16x8*>(As + (wm + i * 16 + mrow) * LDP + kc * 32 + g * 8);
#pragma unroll
            for (int j = 0; j < 4; ++j)
                b[j] = *reinterpret_cast<const bf16x8*>(Bs + (wn + j * 16 + mrow) * LDP + kc * 32 + g * 8);
#pragma unroll
            for (int i = 0; i < 4; ++i)
#pragma unroll
                for (int j = 0; j < 4; ++j)
                    acc[i][j] = __builtin_amdgcn_mfma_f32_16x16x32_bf16(a[i], b[j], acc[i][j], 0, 0, 0);
        }
        __syncthreads();
    }
    // epilogue: C/D layout col=lane&15, row=g*4+reg
#pragma unroll
    for (int i = 0; i < 4; ++i) {
#pragma unroll
        for (int j = 0; j < 4; ++j) {
            int gn = bn + wn + j * 16 + mrow;
            if (gn >= Nn) continue;
            float bv = bias[gn];
#pragma unroll
            for (int r = 0; r < 4; ++r) {
                int gm = bm + wm + i * 16 + g * 4 + r;
                if (gm >= M) continue;
                float val = acc[i][j][r] + bv;
                if (MODE == 1) {
                    int sec = gn >> 8, cc = gn & 255;
                    if (sec == 0)      QS[(size_t)gm * 512 + cc] = val;
                    else if (sec == 1) KV[(size_t)gm * 512 + (cc >> 2) * 8 + (cc & 3)] = f2bf(val);
                    else if (sec == 2) KV[(size_t)gm * 512 + (cc >> 2) * 8 + 4 + (cc & 3)] = f2bf(val);
                    else               QS[(size_t)gm * 512 + 256 + cc] = val;
                } else {
                    int sec = gn / OUT_F, cc = gn % OUT_F;
                    if (sec == 0)      QS[(size_t)gm * 80 + cc] = val;
                    else if (sec == 1) KV[(size_t)gm * 80 + 2 * cc] = f2bf(val);
                    else if (sec == 2) KV[(size_t)gm * 80 + 2 * cc + 1] = f2bf(val);
                    else               QS[(size_t)gm * 80 + 40 + cc] = val;
                }
            }
        }
    }
}

// ---------------- layer-1 edge kernel: one wave per dst node ----------------
// QS1 row = [Q(256 fp32) | S(256 fp32)]; KV1 row = 64 groups of {4 K bf16, 4 V bf16}
__global__ __launch_bounds__(256) void k_edge1(
        const float* __restrict__ QS, const ushortT* __restrict__ KV,
        const float* __restrict__ bw,
        const int* __restrict__ rowstart, const int* __restrict__ deg,
        const int* __restrict__ col, ushortT* __restrict__ H1b) {
    int gid  = blockIdx.x * blockDim.x + threadIdx.x;
    int node = gid >> 6;
    int lane = threadIdx.x & 63;
    if (node >= N_NODES) return;
    const int c4 = lane * 4;
    const float scale = 0.17677669529663687f;  // 1/sqrt(32)
    float4 q = *reinterpret_cast<const float4*>(QS + (size_t)node * 512 + c4);
    q.x *= scale; q.y *= scale; q.z *= scale; q.w *= scale;

    float m = -INFINITY, l = 0.f;
    float4 acc = make_float4(0.f, 0.f, 0.f, 0.f);
    int start = rowstart[node];
    int d = deg[node];
    for (int t = 0; t < d; ++t) {
        int j = col[start + t];
        ushortx8 kv = *reinterpret_cast<const ushortx8*>(KV + (size_t)j * 512 + lane * 8);
        float part = q.x * bf2f(kv[0]) + q.y * bf2f(kv[1])
                   + q.z * bf2f(kv[2]) + q.w * bf2f(kv[3]);
        part += __shfl_xor(part, 1);
        part += __shfl_xor(part, 2);
        part += __shfl_xor(part, 4);   // alpha for this lane's head
        float nm = fmaxf(m, part);
        float f  = __expf(m - nm);
        float p  = __expf(part - nm);
        l = l * f + p;
        acc.x = acc.x * f + p * bf2f(kv[4]);
        acc.y = acc.y * f + p * bf2f(kv[5]);
        acc.z = acc.z * f + p * bf2f(kv[6]);
        acc.w = acc.w * f + p * bf2f(kv[7]);
        m = nm;
    }
    float inv = (l > 0.f) ? 1.f / l : 0.f;
    float4 o = make_float4(acc.x * inv, acc.y * inv, acc.z * inv, acc.w * inv);
    float4 sk = *reinterpret_cast<const float4*>(QS + (size_t)node * 512 + 256 + c4);
    float4 w0 = *reinterpret_cast<const float4*>(bw + c4);
    float4 w1 = *reinterpret_cast<const float4*>(bw + D1 + c4);
    float4 w2 = *reinterpret_cast<const float4*>(bw + 2 * D1 + c4);
    float part = o.x * w0.x + o.y * w0.y + o.z * w0.z + o.w * w0.w
               + sk.x * w1.x + sk.y * w1.y + sk.z * w1.z + sk.w * w1.w
               + (o.x - sk.x) * w2.x + (o.y - sk.y) * w2.y
               + (o.z - sk.z) * w2.z + (o.w - sk.w) * w2.w;
#pragma unroll
    for (int s = 1; s < 64; s <<= 1) part += __shfl_xor(part, s);
    float beta = 1.f / (1.f + __expf(-part));
    float4 h;
    h.x = beta * sk.x + (1.f - beta) * o.x;
    h.y = beta * sk.y + (1.f - beta) * o.y;
    h.z = beta * sk.z + (1.f - beta) * o.z;
    h.w = beta * sk.w + (1.f - beta) * o.w;
    // ELU (alpha=1)
    h.x = h.x > 0.f ? h.x : __expf(h.x) - 1.f;
    h.y = h.y > 0.f ? h.y : __expf(h.y) - 1.f;
    h.z = h.z > 0.f ? h.z : __expf(h.z) - 1.f;
    h.w = h.w > 0.f ? h.w : __expf(h.w) - 1.f;
    ushort4 hb;
    hb.x = f2bf(h.x); hb.y = f2bf(h.y); hb.z = f2bf(h.z); hb.w = f2bf(h.w);
    *reinterpret_cast<ushort4*>(H1b + (size_t)node * D1 + c4) = hb;
}

// ---------------- layer-2 edge kernel: one wave per dst node, 40 channels ----------------
// QS2 row = [Q(40 fp32) | S(40 fp32)]; KV2 row = 40 pairs {K bf16, V bf16}
__global__ __launch_bounds__(256) void k_edge2(
        const float* __restrict__ QS, const ushortT* __restrict__ KV,
        const float* __restrict__ bw,
        const int* __restrict__ rowstart, const int* __restrict__ deg,
        const int* __restrict__ col, float* __restrict__ out) {
    int gid  = blockIdx.x * blockDim.x + threadIdx.x;
    int node = gid >> 6;
    int lane = threadIdx.x & 63;
    if (node >= N_NODES) return;
    bool act = lane < OUT_F;
    int ln = act ? lane : 0;
    const float scale = 0.15811388300841897f;  // 1/sqrt(40)
    float q = act ? QS[(size_t)node * 80 + ln] * scale : 0.f;

    float m = -INFINITY, l = 0.f, acc = 0.f;
    int start = rowstart[node];
    int d = deg[node];
    for (int t = 0; t < d; ++t) {
        int j = col[start + t];
        unsigned int kv = act ? *reinterpret_cast<const unsigned int*>(KV + (size_t)j * 80 + 2 * ln) : 0u;
        float part = q * bf2f((ushortT)(kv & 0xFFFFu));
#pragma unroll
        for (int s = 1; s < 64; s <<= 1) part += __shfl_xor(part, s);
        float nm = fmaxf(m, part);
        float f  = __expf(m - nm);
        float p  = __expf(part - nm);
        l = l * f + p;
        acc = acc * f + p * bf2f((ushortT)(kv >> 16));
        m = nm;
    }
    float inv = (l > 0.f) ? 1.f / l : 0.f;
    float o  = acc * inv;
    float sk = act ? QS[(size_t)node * 80 + 40 + ln] : 0.f;
    float part = act ? (o * bw[ln] + sk * bw[OUT_F + ln] + (o - sk) * bw[2 * OUT_F + ln]) : 0.f;
#pragma unroll
    for (int s = 1; s < 64; s <<= 1) part += __shfl_xor(part, s);
    float beta = 1.f / (1.f + __expf(-part));
    if (act) out[(size_t)node * OUT_F + lane] = beta * sk + (1.f - beta) * o;
}

// ---------------- launch ----------------
extern "C" void kernel_launch(void* const* d_in, const int* in_sizes, int n_in,
                              void* d_out, int out_size, void* d_ws, size_t ws_size,
                              hipStream_t stream) {
    const float* x   = (const float*)d_in[0];
    const int*   ei  = (const int*)d_in[1];
    const float* q1w = (const float*)d_in[2];
    const float* q1b = (const float*)d_in[3];
    const float* k1w = (const float*)d_in[4];
    const float* k1b = (const float*)d_in[5];
    const float* v1w = (const float*)d_in[6];
    const float* v1b = (const float*)d_in[7];
    const float* s1w = (const float*)d_in[8];
    const float* s1b = (const float*)d_in[9];
    const float* b1w = (const float*)d_in[10];
    const float* q2w = (const float*)d_in[11];
    const float* q2b = (const float*)d_in[12];
    const float* k2w = (const float*)d_in[13];
    const float* k2b = (const float*)d_in[14];
    const float* v2w = (const float*)d_in[15];
    const float* v2b = (const float*)d_in[16];
    const float* s2w = (const float*)d_in[17];
    const float* s2b = (const float*)d_in[18];
    const float* b2w = (const float*)d_in[19];
    float* out = (float*)d_out;

    // ---- workspace layout (byte offsets, all 16B aligned) ----
    char* w = (char*)d_ws;
    float*   QS1 = (float*)w;                            // 50000*512*4 = 102,400,000
    ushortT* KV1 = (ushortT*)(w + 102400000);            // 50000*512*2 =  51,200,000
    ushortT* H1b = (ushortT*)(w + 153600000);            // 50000*256*2 =  25,600,000
    ushortT* xb  = (ushortT*)(w + 179200000);            // 50000*128*2 =  12,800,000
    ushortT* W1T = (ushortT*)(w + 192000000);            // 1024*128*2  =     262,144
    ushortT* W2T = (ushortT*)(w + 192262144);            // 160*256*2   =      81,920
    float*   b1c = (float*)(w + 192344064);              // 1024*4
    float*   b2c = (float*)(w + 192348160);              // 160*4 (pad)
    int* deg      = (int*)(w + 192349184);
    int* cursor   = deg + N_NODES;
    int* gcur     = cursor + N_NODES;
    int* rowstart = gcur + 1;
    int* col      = rowstart + N_NODES;
    // layer-2 packed buffers alias layer-1 (dead after edge1)
    float*   QS2 = QS1;                                  // 50000*80*4 = 16 MB
    ushortT* KV2 = KV1;                                  // 50000*80*2 =  8 MB

    hipMemsetAsync(deg, 0, (2 * (size_t)N_NODES + 1) * sizeof(int), stream);

    k_count<<<(N_EDGES + 255) / 256, 256, 0, stream>>>(ei, deg);
    k_alloc<<<(N_NODES + 255) / 256, 256, 0, stream>>>(deg, rowstart, gcur);
    k_fill <<<(N_EDGES + 255) / 256, 256, 0, stream>>>(ei, rowstart, cursor, col);

    conv_x_bf16<<<(N_NODES * IN_F / 4 + 255) / 256, 256, 0, stream>>>(x, xb);
    build_w1<<<(W1COLS * IN_F + 255) / 256, 256, 0, stream>>>(
        q1w, k1w, v1w, s1w, q1b, k1b, v1b, s1b, W1T, b1c);
    build_w2<<<(W2COLS * D1 + 255) / 256, 256, 0, stream>>>(
        q2w, k2w, v2w, s2w, q2b, k2b, v2b, s2b, W2T, b2c);

    dim3 g1((N_NODES + 127) / 128, W1COLS / 128);
    gemm_mfma_pack<1><<<g1, 256, 0, stream>>>(xb, W1T, b1c, QS1, KV1, N_NODES, IN_F, W1COLS);

    k_edge1<<<(N_NODES * 64) / 256, 256, 0, stream>>>(QS1, KV1, b1w, rowstart, deg, col, H1b);

    dim3 g2((N_NODES + 127) / 128, (W2COLS + 127) / 128);
    gemm_mfma_pack<2><<<g2, 256, 0, stream>>>(H1b, W2T, b2c, QS2, KV2, N_NODES, D1, W2COLS);

    k_edge2<<<(N_NODES * 64) / 256, 256, 0, stream>>>(QS2, KV2, b2w, rowstart, deg, col, out);
}

// Round 4
// 498.995 us; speedup vs baseline: 2.1392x; 1.1772x over previous
//
#include <hip/hip_runtime.h>
#include <cstdint>
#include <cstddef>

#define N_NODES 50000
#define N_EDGES 800000
#define IN_F    128
#define HID     32
#define HEADS   8
#define OUT_F   40
#define D1      256   // HID*HEADS
#define W1COLS  1024  // 4*D1
#define W2COLS  160   // 4*OUT_F

typedef unsigned short ushortT;
typedef unsigned short ushortx8 __attribute__((ext_vector_type(8)));
typedef __bf16 bf16x8 __attribute__((ext_vector_type(8)));
typedef float floatx4 __attribute__((ext_vector_type(4)));

__device__ inline ushortT f2bf(float f) {
    union { float f; unsigned int u; } c; c.f = f;
    unsigned int r = c.u + 0x7FFFu + ((c.u >> 16) & 1u);
    return (ushortT)(r >> 16);
}
__device__ inline float bf2f(ushortT h) {
    union { unsigned int u; float f; } c; c.u = ((unsigned int)h) << 16; return c.f;
}

// ---------------- CSR build (by dst) ----------------
__global__ void k_count(const int* __restrict__ ei, int* __restrict__ deg) {
    int e = blockIdx.x * blockDim.x + threadIdx.x;
    if (e < N_EDGES) atomicAdd(&deg[ei[N_EDGES + e]], 1);
}

__global__ void k_alloc(const int* __restrict__ deg, int* __restrict__ rowstart,
                        int* __restrict__ gcur) {
    int n = blockIdx.x * blockDim.x + threadIdx.x;
    if (n < N_NODES) rowstart[n] = atomicAdd(gcur, deg[n]);
}

__global__ void k_fill(const int* __restrict__ ei, const int* __restrict__ rowstart,
                       int* __restrict__ cursor, int* __restrict__ col) {
    int e = blockIdx.x * blockDim.x + threadIdx.x;
    if (e < N_EDGES) {
        int d = ei[N_EDGES + e];
        int p = atomicAdd(&cursor[d], 1);
        col[rowstart[d] + p] = ei[e];   // store src node id
    }
}

// ---------------- conversions ----------------
__global__ void conv_x_bf16(const float* __restrict__ x, ushortT* __restrict__ xb) {
    int i = blockIdx.x * blockDim.x + threadIdx.x;   // over N*IN/4 float4s
    if (i >= N_NODES * IN_F / 4) return;
    float4 v = reinterpret_cast<const float4*>(x)[i];
    ushort4 o;
    o.x = f2bf(v.x); o.y = f2bf(v.y); o.z = f2bf(v.z); o.w = f2bf(v.w);
    reinterpret_cast<ushort4*>(xb)[i] = o;
}

// W1T[c][k] = w_sel[k][c%256], c in [0,1024), k in [0,128)
__global__ void build_w1(const float* __restrict__ qw, const float* __restrict__ kw,
                         const float* __restrict__ vw, const float* __restrict__ sw,
                         const float* __restrict__ qb, const float* __restrict__ kb,
                         const float* __restrict__ vb, const float* __restrict__ sb,
                         ushortT* __restrict__ WT, float* __restrict__ bcat) {
    int t = blockIdx.x * blockDim.x + threadIdx.x;
    if (t >= W1COLS * IN_F) return;
    int c = t / IN_F, k = t % IN_F;
    int sel = c >> 8, cc = c & 255;
    const float* w = sel == 0 ? qw : sel == 1 ? kw : sel == 2 ? vw : sw;
    WT[(size_t)c * IN_F + k] = f2bf(w[(size_t)k * D1 + cc]);
    if (k == 0) {
        const float* b = sel == 0 ? qb : sel == 1 ? kb : sel == 2 ? vb : sb;
        bcat[c] = b[cc];
    }
}

// W2T[c][k] = w_sel[k][c%40], c in [0,160), k in [0,256)
__global__ void build_w2(const float* __restrict__ qw, const float* __restrict__ kw,
                         const float* __restrict__ vw, const float* __restrict__ sw,
                         const float* __restrict__ qb, const float* __restrict__ kb,
                         const float* __restrict__ vb, const float* __restrict__ sb,
                         ushortT* __restrict__ WT, float* __restrict__ bcat) {
    int t = blockIdx.x * blockDim.x + threadIdx.x;
    if (t >= W2COLS * D1) return;
    int c = t / D1, k = t % D1;
    int sel = c / OUT_F, cc = c % OUT_F;
    const float* w = sel == 0 ? qw : sel == 1 ? kw : sel == 2 ? vw : sw;
    WT[(size_t)c * D1 + k] = f2bf(w[(size_t)k * OUT_F + cc]);
    if (k == 0) {
        const float* b = sel == 0 ? qb : sel == 1 ? kb : sel == 2 ? vb : sb;
        bcat[c] = b[cc];
    }
}

// ---------------- bf16 MFMA GEMM with packed epilogue ----------------
// MODE 1 (layer1, Nn=1024): each 128-col block is one section (Q/K/V/S).
//   Q -> QSh[n*512 + c] (bf16)           S -> QSh[n*512 + 256 + c] (bf16)
//   K -> KV[n*512 + (c>>2)*8 + (c&3)]    V -> KV[n*512 + (c>>2)*8 + 4 + (c&3)]
//   Epilogue: wave-private LDS transpose -> coalesced ushort4 stores.
// MODE 2 (layer2, Nn=160, sections of 40): scatter epilogue (small traffic).
//   Q -> QSf[n*80+c]  K -> KV[n*80+2c]  V -> KV[n*80+2c+1]  S -> QSf[n*80+40+c]
template<int MODE>
__global__ __launch_bounds__(256) void gemm_mfma_pack(
        const ushortT* __restrict__ A, const ushortT* __restrict__ BT,
        const float* __restrict__ bias, float* __restrict__ QSf,
        ushortT* __restrict__ QSh, ushortT* __restrict__ KV,
        int M, int K, int Nn) {
    constexpr int TM = 128, TN = 128, TK = 64, LDP = 72;  // LDS row stride (pad 8)
    __shared__ ushortT As[TM * LDP];
    __shared__ ushortT Bs[TN * LDP];
    int tid = threadIdx.x;
    int lane = tid & 63, wave = tid >> 6;
    int bm = blockIdx.x * TM, bn = blockIdx.y * TN;
    int wm = (wave & 1) * 64, wn = (wave >> 1) * 64;
    int mrow = lane & 15, g = lane >> 4;
    floatx4 acc[4][4] = {};

    for (int k0 = 0; k0 < K; k0 += TK) {
#pragma unroll
        for (int it = 0; it < 4; ++it) {          // A tile: 128x64
            int idx = tid + it * 256;
            int r = idx >> 3, c = (idx & 7) * 8;
            int gm = bm + r;
            ushortx8 val;
            if (gm < M) val = *reinterpret_cast<const ushortx8*>(A + (size_t)gm * K + k0 + c);
            else        val = (ushortx8)0;
            *reinterpret_cast<ushortx8*>(As + r * LDP + c) = val;
        }
#pragma unroll
        for (int it = 0; it < 4; ++it) {          // B tile: 128x64
            int idx = tid + it * 256;
            int r = idx >> 3, c = (idx & 7) * 8;
            int gn = bn + r;
            ushortx8 val;
            if (gn < Nn) val = *reinterpret_cast<const ushortx8*>(BT + (size_t)gn * K + k0 + c);
            else         val = (ushortx8)0;
            *reinterpret_cast<ushortx8*>(Bs + r * LDP + c) = val;
        }
        __syncthreads();
#pragma unroll
        for (int kc = 0; kc < TK / 32; ++kc) {
            bf16x8 a[4], b[4];
#pragma unroll
            for (int i = 0; i < 4; ++i)
                a[i] = *reinterpret_cast<const bf16x8*>(As + (wm + i * 16 + mrow) * LDP + kc * 32 + g * 8);
#pragma unroll
            for (int j = 0; j < 4; ++j)
                b[j] = *reinterpret_cast<const bf16x8*>(Bs + (wn + j * 16 + mrow) * LDP + kc * 32 + g * 8);
#pragma unroll
            for (int i = 0; i < 4; ++i)
#pragma unroll
                for (int j = 0; j < 4; ++j)
                    acc[i][j] = __builtin_amdgcn_mfma_f32_16x16x32_bf16(a[i], b[j], acc[i][j], 0, 0, 0);
        }
        __syncthreads();
    }

    if (MODE == 1) {
        // wave-private LDS transpose (reuse As: 4 waves x 1088 floats = 17.4 KB <= 18.4 KB)
        float* lds = reinterpret_cast<float*>(As) + wave * 1088;
        int sec = blockIdx.y >> 1;                 // 0=Q,1=K,2=V,3=S
        int ccbase = (blockIdx.y & 1) * 128 + wn;  // within-section col base of this wave
        int cb4 = (lane & 15) * 4;
        int rlo = lane >> 4;
        float4 bv = *reinterpret_cast<const float4*>(bias + blockIdx.y * 128 + wn + cb4);
#pragma unroll
        for (int i = 0; i < 4; ++i) {
#pragma unroll
            for (int j = 0; j < 4; ++j)
#pragma unroll
                for (int r = 0; r < 4; ++r)
                    lds[(g * 4 + r) * 68 + j * 16 + mrow] = acc[i][j][r];
            // per-wave LDS ops complete in order: read-after-write safe without barrier
#pragma unroll
            for (int it = 0; it < 4; ++it) {
                int row = it * 4 + rlo;
                int gm = bm + wm + i * 16 + row;
                if (gm >= M) continue;
                float4 v = *reinterpret_cast<float4*>(lds + row * 68 + cb4);
                ushort4 h;
                h.x = f2bf(v.x + bv.x); h.y = f2bf(v.y + bv.y);
                h.z = f2bf(v.z + bv.z); h.w = f2bf(v.w + bv.w);
                int cc = ccbase + cb4;
                ushortT* dst;
                if (sec == 0)      dst = QSh + (size_t)gm * 512 + cc;
                else if (sec == 3) dst = QSh + (size_t)gm * 512 + 256 + cc;
                else if (sec == 1) dst = KV + (size_t)gm * 512 + cc * 2;
                else               dst = KV + (size_t)gm * 512 + cc * 2 + 4;
                *reinterpret_cast<ushort4*>(dst) = h;
            }
        }
    } else {
        // scatter epilogue (layer 2, small)
#pragma unroll
        for (int i = 0; i < 4; ++i) {
#pragma unroll
            for (int j = 0; j < 4; ++j) {
                int gn = bn + wn + j * 16 + mrow;
                if (gn >= Nn) continue;
                float bvs = bias[gn];
#pragma unroll
                for (int r = 0; r < 4; ++r) {
                    int gm = bm + wm + i * 16 + g * 4 + r;
                    if (gm >= M) continue;
                    float val = acc[i][j][r] + bvs;
                    int sec = gn / OUT_F, cc = gn % OUT_F;
                    if (sec == 0)      QSf[(size_t)gm * 80 + cc] = val;
                    else if (sec == 1) KV[(size_t)gm * 80 + 2 * cc] = f2bf(val);
                    else if (sec == 2) KV[(size_t)gm * 80 + 2 * cc + 1] = f2bf(val);
                    else               QSf[(size_t)gm * 80 + 40 + cc] = val;
                }
            }
        }
    }
}

// ---------------- layer-1 edge kernel: one wave per dst node, unroll 2 ----------------
// QSh row = [Q(256 bf16) | S(256 bf16)]; KV row = 64 groups of {4 K bf16, 4 V bf16}
__global__ __launch_bounds__(256) void k_edge1(
        const ushortT* __restrict__ QSh, const ushortT* __restrict__ KV,
        const float* __restrict__ bw,
        const int* __restrict__ rowstart, const int* __restrict__ deg,
        const int* __restrict__ col, ushortT* __restrict__ H1b) {
    int gid  = blockIdx.x * blockDim.x + threadIdx.x;
    int node = gid >> 6;
    int lane = threadIdx.x & 63;
    if (node >= N_NODES) return;
    const float scale = 0.17677669529663687f;  // 1/sqrt(32)
    ushort4 qh = *reinterpret_cast<const ushort4*>(QSh + (size_t)node * 512 + lane * 4);
    float4 q;
    q.x = bf2f(qh.x) * scale; q.y = bf2f(qh.y) * scale;
    q.z = bf2f(qh.z) * scale; q.w = bf2f(qh.w) * scale;

    float m = -INFINITY, l = 0.f;
    float4 acc = make_float4(0.f, 0.f, 0.f, 0.f);
    int start = rowstart[node];
    int d = deg[node];
    int t = 0;
    for (; t + 2 <= d; t += 2) {
        int j0 = col[start + t];
        int j1 = col[start + t + 1];
        ushortx8 kv0 = *reinterpret_cast<const ushortx8*>(KV + (size_t)j0 * 512 + lane * 8);
        ushortx8 kv1 = *reinterpret_cast<const ushortx8*>(KV + (size_t)j1 * 512 + lane * 8);
        float p0 = q.x * bf2f(kv0[0]) + q.y * bf2f(kv0[1]) + q.z * bf2f(kv0[2]) + q.w * bf2f(kv0[3]);
        float p1 = q.x * bf2f(kv1[0]) + q.y * bf2f(kv1[1]) + q.z * bf2f(kv1[2]) + q.w * bf2f(kv1[3]);
        p0 += __shfl_xor(p0, 1);  p1 += __shfl_xor(p1, 1);
        p0 += __shfl_xor(p0, 2);  p1 += __shfl_xor(p1, 2);
        p0 += __shfl_xor(p0, 4);  p1 += __shfl_xor(p1, 4);
        float nm = fmaxf(m, fmaxf(p0, p1));
        float f  = __expf(m - nm);
        float e0 = __expf(p0 - nm);
        float e1 = __expf(p1 - nm);
        l = l * f + e0 + e1;
        acc.x = acc.x * f + e0 * bf2f(kv0[4]) + e1 * bf2f(kv1[4]);
        acc.y = acc.y * f + e0 * bf2f(kv0[5]) + e1 * bf2f(kv1[5]);
        acc.z = acc.z * f + e0 * bf2f(kv0[6]) + e1 * bf2f(kv1[6]);
        acc.w = acc.w * f + e0 * bf2f(kv0[7]) + e1 * bf2f(kv1[7]);
        m = nm;
    }
    if (t < d) {
        int j = col[start + t];
        ushortx8 kv = *reinterpret_cast<const ushortx8*>(KV + (size_t)j * 512 + lane * 8);
        float p0 = q.x * bf2f(kv[0]) + q.y * bf2f(kv[1]) + q.z * bf2f(kv[2]) + q.w * bf2f(kv[3]);
        p0 += __shfl_xor(p0, 1);
        p0 += __shfl_xor(p0, 2);
        p0 += __shfl_xor(p0, 4);
        float nm = fmaxf(m, p0);
        float f  = __expf(m - nm);
        float e0 = __expf(p0 - nm);
        l = l * f + e0;
        acc.x = acc.x * f + e0 * bf2f(kv[4]);
        acc.y = acc.y * f + e0 * bf2f(kv[5]);
        acc.z = acc.z * f + e0 * bf2f(kv[6]);
        acc.w = acc.w * f + e0 * bf2f(kv[7]);
        m = nm;
    }
    float inv = (l > 0.f) ? 1.f / l : 0.f;
    float4 o = make_float4(acc.x * inv, acc.y * inv, acc.z * inv, acc.w * inv);
    ushort4 sh = *reinterpret_cast<const ushort4*>(QSh + (size_t)node * 512 + 256 + lane * 4);
    float4 sk;
    sk.x = bf2f(sh.x); sk.y = bf2f(sh.y); sk.z = bf2f(sh.z); sk.w = bf2f(sh.w);
    const int c4 = lane * 4;
    float4 w0 = *reinterpret_cast<const float4*>(bw + c4);
    float4 w1 = *reinterpret_cast<const float4*>(bw + D1 + c4);
    float4 w2 = *reinterpret_cast<const float4*>(bw + 2 * D1 + c4);
    float part = o.x * w0.x + o.y * w0.y + o.z * w0.z + o.w * w0.w
               + sk.x * w1.x + sk.y * w1.y + sk.z * w1.z + sk.w * w1.w
               + (o.x - sk.x) * w2.x + (o.y - sk.y) * w2.y
               + (o.z - sk.z) * w2.z + (o.w - sk.w) * w2.w;
#pragma unroll
    for (int s = 1; s < 64; s <<= 1) part += __shfl_xor(part, s);
    float beta = 1.f / (1.f + __expf(-part));
    float4 h;
    h.x = beta * sk.x + (1.f - beta) * o.x;
    h.y = beta * sk.y + (1.f - beta) * o.y;
    h.z = beta * sk.z + (1.f - beta) * o.z;
    h.w = beta * sk.w + (1.f - beta) * o.w;
    // ELU (alpha=1)
    h.x = h.x > 0.f ? h.x : __expf(h.x) - 1.f;
    h.y = h.y > 0.f ? h.y : __expf(h.y) - 1.f;
    h.z = h.z > 0.f ? h.z : __expf(h.z) - 1.f;
    h.w = h.w > 0.f ? h.w : __expf(h.w) - 1.f;
    ushort4 hb;
    hb.x = f2bf(h.x); hb.y = f2bf(h.y); hb.z = f2bf(h.z); hb.w = f2bf(h.w);
    *reinterpret_cast<ushort4*>(H1b + (size_t)node * D1 + c4) = hb;
}

// ---------------- layer-2 edge kernel: one wave per dst node, unroll 2 ----------------
// QSf row = [Q(40 fp32) | S(40 fp32)]; KV row = 40 pairs {K bf16, V bf16}
__global__ __launch_bounds__(256) void k_edge2(
        const float* __restrict__ QS, const ushortT* __restrict__ KV,
        const float* __restrict__ bw,
        const int* __restrict__ rowstart, const int* __restrict__ deg,
        const int* __restrict__ col, float* __restrict__ out) {
    int gid  = blockIdx.x * blockDim.x + threadIdx.x;
    int node = gid >> 6;
    int lane = threadIdx.x & 63;
    if (node >= N_NODES) return;
    bool act = lane < OUT_F;
    int ln = act ? lane : 0;
    const float scale = 0.15811388300841897f;  // 1/sqrt(40)
    float q = act ? QS[(size_t)node * 80 + ln] * scale : 0.f;

    float m = -INFINITY, l = 0.f, acc = 0.f;
    int start = rowstart[node];
    int d = deg[node];
    int t = 0;
    for (; t + 2 <= d; t += 2) {
        int j0 = col[start + t];
        int j1 = col[start + t + 1];
        unsigned int kv0 = act ? *reinterpret_cast<const unsigned int*>(KV + (size_t)j0 * 80 + 2 * ln) : 0u;
        unsigned int kv1 = act ? *reinterpret_cast<const unsigned int*>(KV + (size_t)j1 * 80 + 2 * ln) : 0u;
        float p0 = q * bf2f((ushortT)(kv0 & 0xFFFFu));
        float p1 = q * bf2f((ushortT)(kv1 & 0xFFFFu));
#pragma unroll
        for (int s = 1; s < 64; s <<= 1) { p0 += __shfl_xor(p0, s); p1 += __shfl_xor(p1, s); }
        float nm = fmaxf(m, fmaxf(p0, p1));
        float f  = __expf(m - nm);
        float e0 = __expf(p0 - nm);
        float e1 = __expf(p1 - nm);
        l = l * f + e0 + e1;
        acc = acc * f + e0 * bf2f((ushortT)(kv0 >> 16)) + e1 * bf2f((ushortT)(kv1 >> 16));
        m = nm;
    }
    if (t < d) {
        int j = col[start + t];
        unsigned int kv = act ? *reinterpret_cast<const unsigned int*>(KV + (size_t)j * 80 + 2 * ln) : 0u;
        float p0 = q * bf2f((ushortT)(kv & 0xFFFFu));
#pragma unroll
        for (int s = 1; s < 64; s <<= 1) p0 += __shfl_xor(p0, s);
        float nm = fmaxf(m, p0);
        float f  = __expf(m - nm);
        float e0 = __expf(p0 - nm);
        l = l * f + e0;
        acc = acc * f + e0 * bf2f((ushortT)(kv >> 16));
        m = nm;
    }
    float inv = (l > 0.f) ? 1.f / l : 0.f;
    float o  = acc * inv;
    float sk = act ? QS[(size_t)node * 80 + 40 + ln] : 0.f;
    float part = act ? (o * bw[ln] + sk * bw[OUT_F + ln] + (o - sk) * bw[2 * OUT_F + ln]) : 0.f;
#pragma unroll
    for (int s = 1; s < 64; s <<= 1) part += __shfl_xor(part, s);
    float beta = 1.f / (1.f + __expf(-part));
    if (act) out[(size_t)node * OUT_F + lane] = beta * sk + (1.f - beta) * o;
}

// ---------------- launch ----------------
extern "C" void kernel_launch(void* const* d_in, const int* in_sizes, int n_in,
                              void* d_out, int out_size, void* d_ws, size_t ws_size,
                              hipStream_t stream) {
    const float* x   = (const float*)d_in[0];
    const int*   ei  = (const int*)d_in[1];
    const float* q1w = (const float*)d_in[2];
    const float* q1b = (const float*)d_in[3];
    const float* k1w = (const float*)d_in[4];
    const float* k1b = (const float*)d_in[5];
    const float* v1w = (const float*)d_in[6];
    const float* v1b = (const float*)d_in[7];
    const float* s1w = (const float*)d_in[8];
    const float* s1b = (const float*)d_in[9];
    const float* b1w = (const float*)d_in[10];
    const float* q2w = (const float*)d_in[11];
    const float* q2b = (const float*)d_in[12];
    const float* k2w = (const float*)d_in[13];
    const float* k2b = (const float*)d_in[14];
    const float* v2w = (const float*)d_in[15];
    const float* v2b = (const float*)d_in[16];
    const float* s2w = (const float*)d_in[17];
    const float* s2b = (const float*)d_in[18];
    const float* b2w = (const float*)d_in[19];
    float* out = (float*)d_out;

    // ---- workspace layout (byte offsets, 16B aligned) ----
    char* w = (char*)d_ws;
    ushortT* QSh = (ushortT*)w;                          // 50000*512*2 = 51,200,000
    ushortT* KV1 = (ushortT*)(w + 51200000);             // 50000*512*2 = 51,200,000
    ushortT* H1b = (ushortT*)(w + 102400000);            // 50000*256*2 = 25,600,000
    ushortT* xb  = (ushortT*)(w + 128000000);            // 50000*128*2 = 12,800,000
    ushortT* W1T = (ushortT*)(w + 140800000);            // 1024*128*2  =    262,144
    ushortT* W2T = (ushortT*)(w + 141062144);            // 160*256*2   =     81,920
    float*   b1c = (float*)(w + 141144064);              // 1024*4
    float*   b2c = (float*)(w + 141148160);              // 160*4 (pad)
    int* deg      = (int*)(w + 141149184);
    int* cursor   = deg + N_NODES;
    int* gcur     = cursor + N_NODES;
    int* rowstart = gcur + 1;
    int* col      = rowstart + N_NODES;
    // layer-2 packed buffers alias layer-1 (dead after edge1)
    float*   QS2 = (float*)w;                            // 50000*80*4 = 16 MB
    ushortT* KV2 = KV1;                                  // 50000*80*2 =  8 MB

    hipMemsetAsync(deg, 0, (2 * (size_t)N_NODES + 1) * sizeof(int), stream);

    k_count<<<(N_EDGES + 255) / 256, 256, 0, stream>>>(ei, deg);
    k_alloc<<<(N_NODES + 255) / 256, 256, 0, stream>>>(deg, rowstart, gcur);
    k_fill <<<(N_EDGES + 255) / 256, 256, 0, stream>>>(ei, rowstart, cursor, col);

    conv_x_bf16<<<(N_NODES * IN_F / 4 + 255) / 256, 256, 0, stream>>>(x, xb);
    build_w1<<<(W1COLS * IN_F + 255) / 256, 256, 0, stream>>>(
        q1w, k1w, v1w, s1w, q1b, k1b, v1b, s1b, W1T, b1c);
    build_w2<<<(W2COLS * D1 + 255) / 256, 256, 0, stream>>>(
        q2w, k2w, v2w, s2w, q2b, k2b, v2b, s2b, W2T, b2c);

    dim3 g1((N_NODES + 127) / 128, W1COLS / 128);
    gemm_mfma_pack<1><<<g1, 256, 0, stream>>>(xb, W1T, b1c, nullptr, QSh, KV1,
                                              N_NODES, IN_F, W1COLS);

    k_edge1<<<(N_NODES * 64) / 256, 256, 0, stream>>>(QSh, KV1, b1w, rowstart, deg, col, H1b);

    dim3 g2((N_NODES + 127) / 128, (W2COLS + 127) / 128);
    gemm_mfma_pack<2><<<g2, 256, 0, stream>>>(H1b, W2T, b2c, QS2, nullptr, KV2,
                                              N_NODES, D1, W2COLS);

    k_edge2<<<(N_NODES * 64) / 256, 256, 0, stream>>>(QS2, KV2, b2w, rowstart, deg, col, out);
}